// Round 12
// baseline (124.038 us; speedup 1.0000x reference)
//
#include <hip/hip_runtime.h>

#define HW 103680           // 240*432
#define WORDS 1620          // HW/64 (= 405 groups * 4 ballot-words)
#define NGRP 405            // 256-pixel groups per row
#define NP 256
#define NO 24
#define ND 256
#define EPSF 1e-8f
#define OUTM (NO*HW)        // 2488320
#define NBLK 512
#define NWAVE (NBLK*4)      // 2048
#define PACK_ITEMS (280*NGRP)   // 113400
#define PACK_PER_WAVE 56        // ceil(113400/2048)
#define GCHUNK 20               // groups per outmask block
#define NGC 21                  // chunks per row o (21*20=420 >= 405)
#define EP1 0x51D00001u
#define EP2 0x51D00002u
#define LSTRIDE 16              // one polled u32 per 64B cache line (contention=1)

typedef unsigned long long u64;

// DPP wave-64 sum (bitwise-identical tree to xor butterfly; verified absmax 0.0)
__device__ __forceinline__ float waveRedSum(float v) {
  v += __int_as_float(__builtin_amdgcn_update_dpp(0, __float_as_int(v), 0x111, 0xf, 0xf, false));
  v += __int_as_float(__builtin_amdgcn_update_dpp(0, __float_as_int(v), 0x112, 0xf, 0xf, false));
  v += __int_as_float(__builtin_amdgcn_update_dpp(0, __float_as_int(v), 0x114, 0xf, 0xf, false));
  v += __int_as_float(__builtin_amdgcn_update_dpp(0, __float_as_int(v), 0x118, 0xf, 0xf, false));
  v += __int_as_float(__builtin_amdgcn_update_dpp(0, __float_as_int(v), 0x142, 0xf, 0xf, false));
  v += __int_as_float(__builtin_amdgcn_update_dpp(0, __float_as_int(v), 0x143, 0xf, 0xf, false));
  return __int_as_float(__builtin_amdgcn_readlane(__float_as_int(v), 63));
}
__device__ __forceinline__ float waveRedMax(float v) {
  int vi = __float_as_int(v);
  v = fmaxf(v, __int_as_float(__builtin_amdgcn_update_dpp(vi, vi, 0x111, 0xf, 0xf, false))); vi = __float_as_int(v);
  v = fmaxf(v, __int_as_float(__builtin_amdgcn_update_dpp(vi, vi, 0x112, 0xf, 0xf, false))); vi = __float_as_int(v);
  v = fmaxf(v, __int_as_float(__builtin_amdgcn_update_dpp(vi, vi, 0x114, 0xf, 0xf, false))); vi = __float_as_int(v);
  v = fmaxf(v, __int_as_float(__builtin_amdgcn_update_dpp(vi, vi, 0x118, 0xf, 0xf, false))); vi = __float_as_int(v);
  v = fmaxf(v, __int_as_float(__builtin_amdgcn_update_dpp(vi, vi, 0x142, 0xf, 0xf, false))); vi = __float_as_int(v);
  v = fmaxf(v, __int_as_float(__builtin_amdgcn_update_dpp(vi, vi, 0x143, 0xf, 0xf, false)));
  return __int_as_float(__builtin_amdgcn_readlane(__float_as_int(v), 63));
}

// Flag-array grid barrier v3 — semantics identical to the PASSING round-11
// barrier (epoch exchanges, RMW polling, fences, poll caps). Only the
// contention topology changed: every polled word sits on its OWN 64B line
// (R11 had 512 pollers RMW-ing one line -> ~65us serialization per barrier),
// and the release is a per-block word written in parallel by block 0's threads.
__device__ __forceinline__ void gridBarrier(unsigned* flags, unsigned* rel, unsigned epoch) {
  __syncthreads();
  if (threadIdx.x == 0) {
    __threadfence();   // release: this block's global writes -> device-visible
    __hip_atomic_exchange(flags + blockIdx.x * LSTRIDE, epoch,
                          __ATOMIC_RELEASE, __HIP_MEMORY_SCOPE_AGENT);
  }
  if (blockIdx.x == 0) {
    for (int i = threadIdx.x; i < NBLK; i += 256) {       // 2 private lines/thread
      int it = 0;
      while (__hip_atomic_fetch_add(flags + i * LSTRIDE, 0u,
                                    __ATOMIC_RELAXED, __HIP_MEMORY_SCOPE_AGENT) != epoch
             && it++ < (1 << 17))
        __builtin_amdgcn_s_sleep(4);
    }
    __syncthreads();
    for (int i = threadIdx.x; i < NBLK; i += 256)
      __hip_atomic_exchange(rel + i * LSTRIDE, epoch,
                            __ATOMIC_RELEASE, __HIP_MEMORY_SCOPE_AGENT);
  }
  if (threadIdx.x == 0) {
    int it = 0;
    while (__hip_atomic_fetch_add(rel + blockIdx.x * LSTRIDE, 0u,
                                  __ATOMIC_RELAXED, __HIP_MEMORY_SCOPE_AGENT) != epoch
           && it++ < (1 << 17))
      __builtin_amdgcn_s_sleep(4);
    __threadfence();   // acquire: drop stale cached lines before reading peers' data
  }
  __syncthreads();
}

__global__ __launch_bounds__(256) void fused_kernel(
    const float* __restrict__ pf, const float* __restrict__ pm,
    const float* __restrict__ tf, const float* __restrict__ ml,
    const float* __restrict__ sc, float* __restrict__ out,
    u64* __restrict__ bbits, u64* __restrict__ abits,
    float* __restrict__ Cm, unsigned* __restrict__ flags,
    unsigned* __restrict__ rel) {
  int tid = threadIdx.x;
  int lane = tid & 63;
  int wv = tid >> 6;                      // wave in block, 0..3
  int W = blockIdx.x * 4 + wv;            // global wave id, 0..2047

  // ---------- phase 1: bit-pack both mask matrices ----------
  {
    int i0 = W * PACK_PER_WAVE;
#pragma unroll 2
    for (int j = 0; j < PACK_PER_WAVE; ++j) {
      int i = i0 + j;
      if (i >= PACK_ITEMS) break;
      int row = i / NGRP;
      int g = i - row * NGRP;
      const float* rp; u64* bits;
      if (row < NP) { rp = pm + (size_t)row * HW;        bits = bbits + (size_t)row * WORDS; }
      else          { rp = ml + (size_t)(row - NP) * HW; bits = abits + (size_t)(row - NP) * WORDS; }
      float4 v = *(const float4*)(rp + g * 256 + lane * 4);
      u64 m0 = __ballot(v.x != 0.0f);
      u64 m1 = __ballot(v.y != 0.0f);
      u64 m2 = __ballot(v.z != 0.0f);
      u64 m3 = __ballot(v.w != 0.0f);
      if (lane == 0) {
        ulonglong2 s0; s0.x = m0; s0.y = m1;
        ulonglong2 s1; s1.x = m2; s1.y = m3;
        *(ulonglong2*)(bits + g * 4)     = s0;
        *(ulonglong2*)(bits + g * 4 + 2) = s1;
      }
    }
  }
  gridBarrier(flags, rel, EP1);

  // ---------- phase 2: cost matrix C[o][p] = -(0.5*cos + 0.5*iou) ----------
  {
#pragma unroll 1
    for (int q = 0; q < 3; ++q) {
      int wid = W + q * NWAVE;            // 0..6143, exactly 3 per wave
      int o = wid >> 8, p = wid & 255;
      float4 f = *(const float4*)(pf + p * ND + lane * 4);
      float4 a = *(const float4*)(tf + o * ND + lane * 4);          // t=0
      float4 b = *(const float4*)(tf + (NO + o) * ND + lane * 4);   // t=1
      const u64* arl = abits + (size_t)o * WORDS + lane;
      const u64* brl = bbits + (size_t)p * WORDS + lane;
      int cnt = 0, ucnt = 0;
#pragma unroll 5
      for (int k = 0; k < 25; ++k) {
        u64 av = arl[k * 64], bv = brl[k * 64];
        cnt  += (int)__popcll(av & bv);
        ucnt += (int)__popcll(av | bv);
      }
      if (lane < WORDS - 1600) {          // tail words 1600..1619
        u64 av = arl[1600], bv = brl[1600];
        cnt  += (int)__popcll(av & bv);
        ucnt += (int)__popcll(av | bv);
      }
      float inter = waveRedSum((float)cnt);
      float uni   = waveRedSum((float)ucnt);
      float nf = waveRedSum(f.x*f.x + f.y*f.y + f.z*f.z + f.w*f.w);
      float na = waveRedSum(a.x*a.x + a.y*a.y + a.z*a.z + a.w*a.w);
      float nb = waveRedSum(b.x*b.x + b.y*b.y + b.z*b.z + b.w*b.w);
      float d0 = waveRedSum(a.x*f.x + a.y*f.y + a.z*f.z + a.w*f.w);
      float d1 = waveRedSum(b.x*f.x + b.y*f.y + b.z*f.z + b.w*f.w);
      if (lane == 0) {
        float invf = 1.0f / (sqrtf(nf) + EPSF);
        float inva = 1.0f / (sqrtf(na) + EPSF);
        float invb = 1.0f / (sqrtf(nb) + EPSF);
        float fs  = (d0 * inva + d1 * invb) * invf * 0.5f;   // /T (T=2)
        float iou = inter / (uni + EPSF);
        Cm[wid] = -(fs * 0.5f + iou * 0.5f);
      }
    }
  }
  gridBarrier(flags, rel, EP2);

  // ---------- phase 3+4: per-block redundant solve (LDS nz) + outmask ----------
  int b = blockIdx.x;
  if (b >= NO * NGC) return;              // 504 active blocks
  int o = b / NGC, gc = b - o * NGC;

  __shared__ int   s_nzidx[NP];
  __shared__ float s_nzval[NP];
  __shared__ int   s_nzcnt;

  {
    // all 4 waves compute the relaxation redundantly (identical results)
    float4 c4 = *(const float4*)(Cm + o * NP + lane * 4);
    float C[4] = {c4.x, c4.y, c4.z, c4.w};
    float sim[4], X[4], Xs[4];
#pragma unroll
    for (int j = 0; j < 4; ++j) {
      sim[j] = -C[j];
      X[j] = 1.0f / 256.0f;
      Xs[j] = 0.0f;
    }
    for (int it = 0; it < 20; ++it) {
#pragma unroll
      for (int j = 0; j < 4; ++j) X[j] = X[j] - 0.1f * C[j];
      for (int k = 0; k < 5; ++k) {
#pragma unroll
        for (int j = 0; j < 4; ++j) X[j] = fminf(fmaxf(X[j], 0.0f), 1.0f);
        float s = waveRedSum((X[0] + X[1]) + (X[2] + X[3]));
#pragma unroll
        for (int j = 0; j < 4; ++j) X[j] = X[j] / (s + EPSF);
      }
#pragma unroll
      for (int j = 0; j < 4; ++j) Xs[j] += X[j];
    }
    float R[4], bx[4];
#pragma unroll
    for (int j = 0; j < 4; ++j) {
      R[j] = Xs[j] / 20.0f;
      bx[j] = (R[j] > 0.01f) ? R[j] : 0.0f;
    }
    if (wv == 0) {
      // wave 0 compacts nonzeros into LDS (p ascending)
      unsigned long long lt = (1ull << lane) - 1ull;
      int base = 0;
#pragma unroll
      for (int j = 0; j < 4; ++j) {
        unsigned long long m = __ballot(bx[j] != 0.0f);
        if (bx[j] != 0.0f) {
          int pos = base + (int)__popcll(m & lt);
          s_nzidx[pos] = lane * 4 + j;
          s_nzval[pos] = bx[j];
        }
        base += (int)__popcll(m);
      }
      if (lane == 0) s_nzcnt = base;
      // scores (once per o: the gc==0 block)
      if (gc == 0) {
        float mv = -1e30f;
#pragma unroll
        for (int j = 0; j < 4; ++j)
          mv = fmaxf(mv, fminf(fmaxf(R[j], 0.0f), 1.0f) * sim[j]);
        mv = waveRedMax(mv);
        float4 sc4 = *(const float4*)(sc + lane * 4);
        float dv = waveRedSum(((sc4.x * bx[0]) + (sc4.y * bx[1])) + ((sc4.z * bx[2]) + (sc4.w * bx[3])));
        if (lane == 0) { out[OUTM + o] = mv; out[OUTM + NO + o] = dv; }
      }
    }
  }
  __syncthreads();

  // outmask: this block covers groups [gc*GCHUNK, gc*GCHUNK+GCHUNK) of row o
  int cnt = s_nzcnt;
  for (int k = wv; k < GCHUNK; k += 4) {
    int g = gc * GCHUNK + k;
    if (g >= NGRP) break;
    float ax = 0.0f, ay = 0.0f, az = 0.0f, aw = 0.0f;
    for (int t = 0; t < cnt; ++t) {
      int p   = s_nzidx[t];
      float v = s_nzval[t];
      const u64* wp = bbits + (size_t)p * WORDS + g * 4;
      u64 m0 = wp[0], m1 = wp[1], m2 = wp[2], m3 = wp[3];
      ax += ((m0 >> lane) & 1ull) ? v : 0.0f;
      ay += ((m1 >> lane) & 1ull) ? v : 0.0f;
      az += ((m2 >> lane) & 1ull) ? v : 0.0f;
      aw += ((m3 >> lane) & 1ull) ? v : 0.0f;
    }
    *(float4*)(out + (size_t)o * HW + g * 256 + lane * 4) = make_float4(ax, ay, az, aw);
  }
}

extern "C" void kernel_launch(void* const* d_in, const int* in_sizes, int n_in,
                              void* d_out, int out_size, void* d_ws, size_t ws_size,
                              hipStream_t stream) {
  const float* pf = (const float*)d_in[0];   // proposed_feature [256][256]
  const float* pm = (const float*)d_in[1];   // proposed_mask    [256][240][432]
  const float* tf = (const float*)d_in[2];   // template_feature [2][24][256]
  const float* ml = (const float*)d_in[3];   // mask_last_occ.   [24][240][432]
  const float* sc = (const float*)d_in[4];   // proposal_score   [256]
  float* out = (float*)d_out;
  char* ws = (char*)d_ws;

  // ws layout (bytes):
  u64*      bbits = (u64*)(ws);                  // 256*1620*8 = 3,317,760
  u64*      abits = (u64*)(ws + 3317760);        // 24*1620*8  =   311,040  -> ends 3,628,800
  float*    Cm    = (float*)(ws + 3628800);      // 24*256*4   =    24,576  -> ends 3,653,376
  unsigned* flags = (unsigned*)(ws + 3653376);   // 512 lines * 64B = 32,768 -> ends 3,686,144
  unsigned* rel   = (unsigned*)(ws + 3686144);   // 512 lines * 64B = 32,768 -> ends 3,718,912

  hipLaunchKernelGGL(fused_kernel, dim3(NBLK), dim3(256), 0, stream,
                     pf, pm, tf, ml, sc, out, bbits, abits, Cm, flags, rel);
}

// Round 14
// 54.637 us; speedup vs baseline: 2.2702x; 2.2702x over previous
//
#include <hip/hip_runtime.h>

#define HW 103680           // 240*432
#define WORDS 1620          // HW/64 (= 405 groups * 4 ballot-words)
#define NGRP 405            // 256-pixel groups per row
#define NP 256
#define NO 24
#define ND 256
#define EPSF 1e-8f
#define OUTM (NO*HW)        // 2488320
#define NCHUNK 26           // chunks per row: 25 full (16 groups) + 1 partial (5)

typedef unsigned long long u64;
typedef float vfloat4 __attribute__((ext_vector_type(4)));   // native vec for nontemporal builtin

// DPP wave-64 sum (bitwise-identical tree to xor butterfly; verified absmax 0.0)
__device__ __forceinline__ float waveRedSum(float v) {
  v += __int_as_float(__builtin_amdgcn_update_dpp(0, __float_as_int(v), 0x111, 0xf, 0xf, false));
  v += __int_as_float(__builtin_amdgcn_update_dpp(0, __float_as_int(v), 0x112, 0xf, 0xf, false));
  v += __int_as_float(__builtin_amdgcn_update_dpp(0, __float_as_int(v), 0x114, 0xf, 0xf, false));
  v += __int_as_float(__builtin_amdgcn_update_dpp(0, __float_as_int(v), 0x118, 0xf, 0xf, false));
  v += __int_as_float(__builtin_amdgcn_update_dpp(0, __float_as_int(v), 0x142, 0xf, 0xf, false));
  v += __int_as_float(__builtin_amdgcn_update_dpp(0, __float_as_int(v), 0x143, 0xf, 0xf, false));
  return __int_as_float(__builtin_amdgcn_readlane(__float_as_int(v), 63));
}
__device__ __forceinline__ float waveRedMax(float v) {
  int vi = __float_as_int(v);
  v = fmaxf(v, __int_as_float(__builtin_amdgcn_update_dpp(vi, vi, 0x111, 0xf, 0xf, false))); vi = __float_as_int(v);
  v = fmaxf(v, __int_as_float(__builtin_amdgcn_update_dpp(vi, vi, 0x112, 0xf, 0xf, false))); vi = __float_as_int(v);
  v = fmaxf(v, __int_as_float(__builtin_amdgcn_update_dpp(vi, vi, 0x114, 0xf, 0xf, false))); vi = __float_as_int(v);
  v = fmaxf(v, __int_as_float(__builtin_amdgcn_update_dpp(vi, vi, 0x118, 0xf, 0xf, false))); vi = __float_as_int(v);
  v = fmaxf(v, __int_as_float(__builtin_amdgcn_update_dpp(vi, vi, 0x142, 0xf, 0xf, false))); vi = __float_as_int(v);
  v = fmaxf(v, __int_as_float(__builtin_amdgcn_update_dpp(vi, vi, 0x143, 0xf, 0xf, false)));
  return __int_as_float(__builtin_amdgcn_readlane(__float_as_int(v), 63));
}

// --- pack with COALESCED stores: one wave = one 16-group chunk = 64 words.
// Ballot words are wave-uniform; per-lane select assigns word L to lane L,
// then ONE coalesced 512B store per chunk (vs 227K divergent 16B stores).
// Word values/order byte-identical to all verified rounds (word g*4+c).
__global__ __launch_bounds__(256) void pack_kernel(const float* __restrict__ pm,
                                                   const float* __restrict__ ml,
                                                   u64* __restrict__ bbits,
                                                   u64* __restrict__ abits) {
  int W = blockIdx.x * 4 + (threadIdx.x >> 6);   // chunk id, 0..7279
  int lane = threadIdx.x & 63;
  int row = W / NCHUNK;                          // 0..279
  int cidx = W - row * NCHUNK;                   // 0..25
  const float* rp; u64* bits;
  if (row < NP) { rp = pm + (size_t)row * HW;        bits = bbits + (size_t)row * WORDS; }
  else          { rp = ml + (size_t)(row - NP) * HW; bits = abits + (size_t)(row - NP) * WORDS; }
  int g0 = cidx * 16;
  int k4 = lane >> 2, c = lane & 3;
  u64 myword = 0;
  if (cidx != 25) {
#pragma unroll
    for (int k = 0; k < 16; ++k) {
      vfloat4 v = __builtin_nontemporal_load((const vfloat4*)(rp + (size_t)(g0 + k) * 256 + lane * 4));
      u64 m0 = __ballot(v.x != 0.0f);
      u64 m1 = __ballot(v.y != 0.0f);
      u64 m2 = __ballot(v.z != 0.0f);
      u64 m3 = __ballot(v.w != 0.0f);
      u64 s = (c == 0) ? m0 : (c == 1) ? m1 : (c == 2) ? m2 : m3;
      if (k4 == k) myword = s;
    }
    bits[g0 * 4 + lane] = myword;                // coalesced 512B
  } else {
#pragma unroll
    for (int k = 0; k < 5; ++k) {                // groups 400..404
      vfloat4 v = __builtin_nontemporal_load((const vfloat4*)(rp + (size_t)(g0 + k) * 256 + lane * 4));
      u64 m0 = __ballot(v.x != 0.0f);
      u64 m1 = __ballot(v.y != 0.0f);
      u64 m2 = __ballot(v.z != 0.0f);
      u64 m3 = __ballot(v.w != 0.0f);
      u64 s = (c == 0) ? m0 : (c == 1) ? m1 : (c == 2) ? m2 : m3;
      if (k4 == k) myword = s;
    }
    if (lane < 20) bits[g0 * 4 + lane] = myword; // words 1600..1619
  }
}

// --- fused cost matrix: C[o][p] = -(0.5*feature_sim + 0.5*iou). One wave/(o,p).
//     UNCHANGED from the round-7-verified kernel. ---
__global__ __launch_bounds__(256) void interfeat_kernel(const u64* __restrict__ ab,
                                                        const u64* __restrict__ bb,
                                                        const float* __restrict__ pf,
                                                        const float* __restrict__ tf,
                                                        float* __restrict__ C) {
  int wid = (blockIdx.x * 256 + threadIdx.x) >> 6;   // 0..6143
  int lane = threadIdx.x & 63;
  int o = wid >> 8, p = wid & 255;
  float4 f = *(const float4*)(pf + p * ND + lane * 4);
  float4 a = *(const float4*)(tf + o * ND + lane * 4);          // t=0
  float4 b = *(const float4*)(tf + (NO + o) * ND + lane * 4);   // t=1
  const u64* arl = ab + (size_t)o * WORDS + lane;
  const u64* brl = bb + (size_t)p * WORDS + lane;
  int cnt = 0, ucnt = 0;
#pragma unroll 5
  for (int k = 0; k < 25; ++k) {
    u64 av = arl[k * 64], bv = brl[k * 64];
    cnt  += (int)__popcll(av & bv);
    ucnt += (int)__popcll(av | bv);
  }
  if (lane < WORDS - 1600) {                        // tail words 1600..1619
    u64 av = arl[1600], bv = brl[1600];
    cnt  += (int)__popcll(av & bv);
    ucnt += (int)__popcll(av | bv);
  }
  float inter = waveRedSum((float)cnt);
  float uni   = waveRedSum((float)ucnt);
  float nf = waveRedSum(f.x*f.x + f.y*f.y + f.z*f.z + f.w*f.w);
  float na = waveRedSum(a.x*a.x + a.y*a.y + a.z*a.z + a.w*a.w);
  float nb = waveRedSum(b.x*b.x + b.y*b.y + b.z*b.z + b.w*b.w);
  float d0 = waveRedSum(a.x*f.x + a.y*f.y + a.z*f.z + a.w*f.w);
  float d1 = waveRedSum(b.x*f.x + b.y*f.y + b.z*f.z + b.w*f.w);
  if (lane == 0) {
    float invf = 1.0f / (sqrtf(nf) + EPSF);
    float inva = 1.0f / (sqrtf(na) + EPSF);
    float invb = 1.0f / (sqrtf(nb) + EPSF);
    float fs  = (d0 * inva + d1 * invb) * invf * 0.5f;   // /T (T=2)
    float iou = inter / (uni + EPSF);
    C[wid] = -(fs * 0.5f + iou * 0.5f);
  }
}

// --- solve + outmask fused: one block per row o (1024 thr = 16 waves).
//     Wave 0: verified solve -> LDS nz + scores. All waves: verified outmask. ---
__global__ __launch_bounds__(1024) void solmask_kernel(const float* __restrict__ Cm,
                                                       const float* __restrict__ score,
                                                       const u64* __restrict__ bb,
                                                       float* __restrict__ out) {
  int o = blockIdx.x;
  int tid = threadIdx.x, lane = tid & 63, w = tid >> 6;   // wave 0..15
  __shared__ int   s_nzidx[NP];
  __shared__ float s_nzval[NP];
  __shared__ int   s_nzcnt;

  if (w == 0) {
    float4 c4 = *(const float4*)(Cm + o * NP + lane * 4);
    float C[4] = {c4.x, c4.y, c4.z, c4.w};
    float sim[4], X[4], Xs[4];
#pragma unroll
    for (int j = 0; j < 4; ++j) {
      sim[j] = -C[j];
      X[j] = 1.0f / 256.0f;
      Xs[j] = 0.0f;
    }
    for (int it = 0; it < 20; ++it) {
#pragma unroll
      for (int j = 0; j < 4; ++j) X[j] = X[j] - 0.1f * C[j];
      for (int k = 0; k < 5; ++k) {
#pragma unroll
        for (int j = 0; j < 4; ++j) X[j] = fminf(fmaxf(X[j], 0.0f), 1.0f);
        float s = waveRedSum((X[0] + X[1]) + (X[2] + X[3]));
#pragma unroll
        for (int j = 0; j < 4; ++j) X[j] = X[j] / (s + EPSF);
      }
#pragma unroll
      for (int j = 0; j < 4; ++j) Xs[j] += X[j];
    }
    float R[4], bx[4];
#pragma unroll
    for (int j = 0; j < 4; ++j) {
      R[j] = Xs[j] / 20.0f;
      bx[j] = (R[j] > 0.01f) ? R[j] : 0.0f;
    }
    // compact nonzeros into LDS (p ascending)
    unsigned long long lt = (1ull << lane) - 1ull;
    int base = 0;
#pragma unroll
    for (int j = 0; j < 4; ++j) {
      unsigned long long m = __ballot(bx[j] != 0.0f);
      if (bx[j] != 0.0f) {
        int pos = base + (int)__popcll(m & lt);
        s_nzidx[pos] = lane * 4 + j;
        s_nzval[pos] = bx[j];
      }
      base += (int)__popcll(m);
    }
    if (lane == 0) s_nzcnt = base;
    // scores
    float mv = -1e30f;
#pragma unroll
    for (int j = 0; j < 4; ++j)
      mv = fmaxf(mv, fminf(fmaxf(R[j], 0.0f), 1.0f) * sim[j]);
    mv = waveRedMax(mv);
    float4 sc4 = *(const float4*)(score + lane * 4);
    float dv = waveRedSum(((sc4.x * bx[0]) + (sc4.y * bx[1])) + ((sc4.z * bx[2]) + (sc4.w * bx[3])));
    if (lane == 0) { out[OUTM + o] = mv; out[OUTM + NO + o] = dv; }
  }
  __syncthreads();

  // outmask: wave w covers groups w, w+16, ... (body identical to verified R7/R12)
  int cnt = s_nzcnt;
  for (int g = w; g < NGRP; g += 16) {
    float ax = 0.0f, ay = 0.0f, az = 0.0f, aw = 0.0f;
    for (int t = 0; t < cnt; ++t) {
      int p   = s_nzidx[t];
      float v = s_nzval[t];
      const u64* wp = bb + (size_t)p * WORDS + g * 4;
      u64 m0 = wp[0], m1 = wp[1], m2 = wp[2], m3 = wp[3];
      ax += ((m0 >> lane) & 1ull) ? v : 0.0f;
      ay += ((m1 >> lane) & 1ull) ? v : 0.0f;
      az += ((m2 >> lane) & 1ull) ? v : 0.0f;
      aw += ((m3 >> lane) & 1ull) ? v : 0.0f;
    }
    *(float4*)(out + (size_t)o * HW + g * 256 + lane * 4) = make_float4(ax, ay, az, aw);
  }
}

extern "C" void kernel_launch(void* const* d_in, const int* in_sizes, int n_in,
                              void* d_out, int out_size, void* d_ws, size_t ws_size,
                              hipStream_t stream) {
  const float* pf = (const float*)d_in[0];   // proposed_feature [256][256]
  const float* pm = (const float*)d_in[1];   // proposed_mask    [256][240][432]
  const float* tf = (const float*)d_in[2];   // template_feature [2][24][256]
  const float* ml = (const float*)d_in[3];   // mask_last_occ.   [24][240][432]
  const float* sc = (const float*)d_in[4];   // proposal_score   [256]
  float* out = (float*)d_out;
  char* ws = (char*)d_ws;

  // ws layout (bytes):
  u64*   bbits = (u64*)(ws);                 // 256*1620*8 = 3,317,760
  u64*   abits = (u64*)(ws + 3317760);       // 24*1620*8  =   311,040 -> ends 3,628,800
  float* Cm    = (float*)(ws + 3628800);     // 24*256*4   =    24,576

  hipLaunchKernelGGL(pack_kernel,      dim3(1820), dim3(256),  0, stream, pm, ml, bbits, abits);
  hipLaunchKernelGGL(interfeat_kernel, dim3(1536), dim3(256),  0, stream, abits, bbits, pf, tf, Cm);
  hipLaunchKernelGGL(solmask_kernel,   dim3(24),   dim3(1024), 0, stream, Cm, sc, bbits, out);
}